// Round 12
// baseline (493.802 us; speedup 1.0000x reference)
//
#include <hip/hip_runtime.h>
#include <hip/hip_fp16.h>

#define EPS 1e-5f

constexpr int B = 4, N = 4096, C = 128, CO = 256, KNN = 16;
constexpr int M = B * N;  // 16384 points total
constexpr int CHUNK = 1024, NCHUNK = 4;

typedef _Float16 half8 __attribute__((ext_vector_type(8)));
typedef float f32x4 __attribute__((ext_vector_type(4)));

// top-16 insertion: list kept as "16 best so far", vmax = current worst.
// rebuild written as nested fmaxf triples so clang can fuse v_max3_f32.
__device__ __forceinline__ void ins16(float key, int idx, float (&dl)[16],
                                      int (&il)[16], float& vmax) {
  if (key < vmax) {
    bool done = false;
#pragma unroll
    for (int j = 0; j < 16; ++j) {
      bool take = (!done) && (dl[j] == vmax);
      if (take) {
        dl[j] = key;
        il[j] = idx;
      }
      done |= take;
    }
    float a = fmaxf(fmaxf(dl[0], dl[1]), dl[2]);
    a = fmaxf(fmaxf(a, dl[3]), dl[4]);
    a = fmaxf(fmaxf(a, dl[5]), dl[6]);
    a = fmaxf(fmaxf(a, dl[7]), dl[8]);
    a = fmaxf(fmaxf(a, dl[9]), dl[10]);
    a = fmaxf(fmaxf(a, dl[11]), dl[12]);
    a = fmaxf(fmaxf(a, dl[13]), dl[14]);
    vmax = fmaxf(a, dl[15]);
  }
}

// ---------------------------------------------------------------------------
// Kernel 1: split x into f16 hi/lo (x = h + m exactly to ~2^-22) + sq norms.
// ---------------------------------------------------------------------------
__global__ __launch_bounds__(256) void k_cvt(const float* __restrict__ x,
                                             _Float16* __restrict__ xh,
                                             _Float16* __restrict__ xm,
                                             float* __restrict__ sq) {
  int t = threadIdx.x;
  int row = blockIdx.x * 64 + (t >> 2);
  int part = t & 3;
  const float* src = x + (size_t)row * C + part * 32;
  _Float16* dh = xh + (size_t)row * C + part * 32;
  _Float16* dm = xm + (size_t)row * C + part * 32;
  float s = 0.f;
#pragma unroll
  for (int i = 0; i < 4; ++i) {
    float4 v0 = *(const float4*)(src + i * 8);
    float4 v1 = *(const float4*)(src + i * 8 + 4);
    float vv[8] = {v0.x, v0.y, v0.z, v0.w, v1.x, v1.y, v1.z, v1.w};
    half8 h, m;
#pragma unroll
    for (int e = 0; e < 8; ++e) {
      s += vv[e] * vv[e];
      _Float16 hh = (_Float16)vv[e];
      h[e] = hh;
      m[e] = (_Float16)(vv[e] - (float)hh);
    }
    *(half8*)(dh + i * 8) = h;
    *(half8*)(dm + i * 8) = m;
  }
  s += __shfl_xor(s, 1);
  s += __shfl_xor(s, 2);
  if (part == 0) sq[row] = s;
}

// ---------------------------------------------------------------------------
// Kernel 2: MFMA distance + per-chunk exact top-16 — BARRIER-FREE.
// A-fragments (candidate tiles) are loaded directly from global (L1/L2-hot,
// 1 MB/batch slice): no LDS, no __syncthreads, no bank conflicts; waves run
// independently so VALU stays fed.  16 queries per wave, 4 waves/block,
// grid = B * 64 qgroups * 4 chunks = 1024 blocks.
// Per-lane top-16 list for query col=lane&15 over its row-quarter; quad-merge
// via shfl; partial lists to pd/pi in transposed [c][q] layout.
// ---------------------------------------------------------------------------
__global__ __launch_bounds__(256) void k_topk(
    const _Float16* __restrict__ xh, const _Float16* __restrict__ xm,
    const float* __restrict__ sq, float* __restrict__ pd, int* __restrict__ pi) {
  int t = threadIdx.x;
  int lane = t & 63, w = t >> 6;
  int bi = blockIdx.x;
  int chunk = bi & 3;
  int qg = (bi >> 2) & 63;
  int b = bi >> 8;
  int col = lane & 15, quad = lane >> 4;
  int qbase = qg * 64 + w * 16;
  const _Float16* xhb = xh + (size_t)b * N * C;
  const _Float16* xmb = xm + (size_t)b * N * C;
  const float* sqb = sq + (size_t)b * N;

  // resident query fragments (B operand): col=lane&15, k=(lane>>4)*8+i
  half8 bh[4], bm[4];
  int qr = qbase + col;
  float sqn = sqb[qr];
#pragma unroll
  for (int kst = 0; kst < 4; ++kst) {
    bh[kst] = *(const half8*)(xhb + (size_t)qr * C + kst * 32 + quad * 8);
    bm[kst] = *(const half8*)(xmb + (size_t)qr * C + kst * 32 + quad * 8);
  }
  float dl[16];
  int il[16];
  float vmax = 3e38f;
#pragma unroll
  for (int j = 0; j < 16; ++j) {
    dl[j] = 3e38f;
    il[j] = 0;
  }
  int mbase = chunk * CHUNK;

  // per-lane A-fragment pointers: row = m0 + col, k-chunk = quad*8 (+kst*32)
  const _Float16* ph = xhb + (size_t)(mbase + col) * C + quad * 8;
  const _Float16* pm = xmb + (size_t)(mbase + col) * C + quad * 8;
  const float* psq = sqb + mbase + quad * 4;

  for (int tile = 0; tile < CHUNK / 16; ++tile) {
    half8 ah0 = *(const half8*)(ph);
    half8 ah1 = *(const half8*)(ph + 32);
    half8 ah2 = *(const half8*)(ph + 64);
    half8 ah3 = *(const half8*)(ph + 96);
    half8 am0 = *(const half8*)(pm);
    half8 am1 = *(const half8*)(pm + 32);
    half8 am2 = *(const half8*)(pm + 64);
    half8 am3 = *(const half8*)(pm + 96);
    f32x4 a0 = {};  // hh accumulation
    f32x4 a1 = {};  // mh + hm accumulation
    a0 = __builtin_amdgcn_mfma_f32_16x16x32_f16(ah0, bh[0], a0, 0, 0, 0);
    a1 = __builtin_amdgcn_mfma_f32_16x16x32_f16(am0, bh[0], a1, 0, 0, 0);
    a1 = __builtin_amdgcn_mfma_f32_16x16x32_f16(ah0, bm[0], a1, 0, 0, 0);
    a0 = __builtin_amdgcn_mfma_f32_16x16x32_f16(ah1, bh[1], a0, 0, 0, 0);
    a1 = __builtin_amdgcn_mfma_f32_16x16x32_f16(am1, bh[1], a1, 0, 0, 0);
    a1 = __builtin_amdgcn_mfma_f32_16x16x32_f16(ah1, bm[1], a1, 0, 0, 0);
    a0 = __builtin_amdgcn_mfma_f32_16x16x32_f16(ah2, bh[2], a0, 0, 0, 0);
    a1 = __builtin_amdgcn_mfma_f32_16x16x32_f16(am2, bh[2], a1, 0, 0, 0);
    a1 = __builtin_amdgcn_mfma_f32_16x16x32_f16(ah2, bm[2], a1, 0, 0, 0);
    a0 = __builtin_amdgcn_mfma_f32_16x16x32_f16(ah3, bh[3], a0, 0, 0, 0);
    a1 = __builtin_amdgcn_mfma_f32_16x16x32_f16(am3, bh[3], a1, 0, 0, 0);
    a1 = __builtin_amdgcn_mfma_f32_16x16x32_f16(ah3, bm[3], a1, 0, 0, 0);

    float4 sqm = *(const float4*)(psq);
    float sqmv[4] = {sqm.x, sqm.y, sqm.z, sqm.w};
    int m0 = mbase + tile * 16;
#pragma unroll
    for (int j = 0; j < 4; ++j) {
      float key = sqn + sqmv[j] - 2.0f * (a0[j] + a1[j]);
      ins16(key, m0 + quad * 4 + j, dl, il, vmax);
    }
    ph += 16 * C;
    pm += 16 * C;
    psq += 16;
  }

  // merge the 4 row-quarters (lanes col, col+16, col+32, col+48)
#pragma unroll
  for (int step = 16; step <= 32; step <<= 1) {
    float pdx[16];
    int pix[16];
#pragma unroll
    for (int j = 0; j < 16; ++j) {
      pdx[j] = __shfl_xor(dl[j], step);
      pix[j] = __shfl_xor(il[j], step);
    }
#pragma unroll
    for (int j = 0; j < 16; ++j) ins16(pdx[j], pix[j], dl, il, vmax);
  }

  if (quad == 0) {
    int q = b * N + qbase + col;  // global query id in [0, M)
#pragma unroll
    for (int j = 0; j < 16; ++j) {
      pd[(size_t)(chunk * 16 + j) * M + q] = dl[j];
      pi[(size_t)(chunk * 16 + j) * M + q] = il[j];
    }
  }
}

// ---------------------------------------------------------------------------
// Kernel 3: merge 4 partial lists (64 candidates) -> final top-16 per query.
// pd/pi are [c][q] so consecutive threads read consecutive addresses.
// ---------------------------------------------------------------------------
__global__ __launch_bounds__(256) void k_merge(const float* __restrict__ pd,
                                               const int* __restrict__ pi,
                                               int* __restrict__ knn) {
  int q = blockIdx.x * 256 + threadIdx.x;
  float dl[16];
  int il[16];
  float vmax = 3e38f;
#pragma unroll
  for (int j = 0; j < 16; ++j) {
    dl[j] = 3e38f;
    il[j] = 0;
  }
#pragma unroll 4
  for (int c = 0; c < NCHUNK * 16; ++c)
    ins16(pd[(size_t)c * M + q], pi[(size_t)c * M + q], dl, il, vmax);
#pragma unroll
  for (int j = 0; j < 16; ++j) knn[(size_t)q * KNN + j] = il[j];
}

// ---------------------------------------------------------------------------
// Kernel 4: A~ = s1 * (x @ W1[0:128,:]), B~ = s1 * (x @ W1[128:256,:])
// ---------------------------------------------------------------------------
__global__ __launch_bounds__(256) void k_gemm1(
    const float* __restrict__ x, const float* __restrict__ W1,
    const float* __restrict__ gamma1, const float* __restrict__ var1,
    float* __restrict__ At, float* __restrict__ Bt) {
  __shared__ float xT[64][68];  // [k][row]
  __shared__ float wS[64][68];  // [k][col]
  int t = threadIdx.x;
  int m0 = blockIdx.x * 64;
  int n0 = blockIdx.y * 64;
  float acc[4][4] = {};
  int r0 = (t & 15) * 4, c0 = (t >> 4) * 4;
  for (int k0 = 0; k0 < C; k0 += 64) {
    {
      int r = t >> 2;
      int cb = (t & 3) * 16;
      const float* src = x + (size_t)(m0 + r) * C + k0 + cb;
#pragma unroll
      for (int i = 0; i < 4; ++i) {
        float4 v = *(const float4*)(src + i * 4);
        xT[cb + i * 4 + 0][r] = v.x;
        xT[cb + i * 4 + 1][r] = v.y;
        xT[cb + i * 4 + 2][r] = v.z;
        xT[cb + i * 4 + 3][r] = v.w;
      }
      int kk = t >> 2;
      int jb = (t & 3) * 16;
      const float* wsrc = (n0 < C) ? (W1 + (size_t)(k0 + kk) * C + (n0 + jb))
                                   : (W1 + (size_t)(C + k0 + kk) * C + (n0 - C + jb));
#pragma unroll
      for (int i = 0; i < 4; ++i)
        *(float4*)&wS[kk][jb + i * 4] = *(const float4*)(wsrc + i * 4);
    }
    __syncthreads();
#pragma unroll 8
    for (int k = 0; k < 64; ++k) {
      f32x4 a = *(const f32x4*)&xT[k][r0];
      f32x4 b = *(const f32x4*)&wS[k][c0];
#pragma unroll
      for (int i = 0; i < 4; ++i)
#pragma unroll
        for (int j = 0; j < 4; ++j) acc[i][j] = fmaf(a[i], b[j], acc[i][j]);
    }
    __syncthreads();
  }
  float* dst = (n0 < C) ? At : Bt;
  int ch0 = (n0 + c0) & (C - 1);
  float s1[4];
#pragma unroll
  for (int j = 0; j < 4; ++j) s1[j] = gamma1[ch0 + j] * rsqrtf(var1[ch0 + j] + EPS);
#pragma unroll
  for (int i = 0; i < 4; ++i) {
    float4 v = make_float4(acc[i][0] * s1[0], acc[i][1] * s1[1],
                           acc[i][2] * s1[2], acc[i][3] * s1[3]);
    *(float4*)&dst[(size_t)(m0 + r0 + i) * C + ch0] = v;
  }
}

// ---------------------------------------------------------------------------
// Kernel 5: per point h = relu(A~ + B~[idx] + beta_f) -> f16, y = h @ W2
// via mfma 16x16x32, BN2 affine, max over k -> out.
// ---------------------------------------------------------------------------
__global__ __launch_bounds__(256) void k_mlp(
    const float* __restrict__ At, const float* __restrict__ Bt,
    const int* __restrict__ knn, const float* __restrict__ W2,
    const float* __restrict__ b1, const float* __restrict__ mean1,
    const float* __restrict__ beta1, const float* __restrict__ gamma1,
    const float* __restrict__ var1, const float* __restrict__ b2,
    const float* __restrict__ mean2, const float* __restrict__ beta2,
    const float* __restrict__ gamma2, const float* __restrict__ var2,
    float* __restrict__ out) {
  __shared__ _Float16 hl[16][136];
  int t = threadIdx.x;
  int lane = t & 63;
  int wave = t >> 6;
  int hk = t >> 4;
  int hc = (t & 15) * 8;

  float beta_f[8];
#pragma unroll
  for (int e = 0; e < 8; ++e) {
    int c = hc + e;
    float s1 = gamma1[c] * rsqrtf(var1[c] + EPS);
    beta_f[e] = s1 * (b1[c] - mean1[c]) + beta1[c];
  }
  float s2r[4], t2r[4];
#pragma unroll
  for (int nt = 0; nt < 4; ++nt) {
    int ch = wave * 64 + nt * 16 + (lane & 15);
    float s2 = gamma2[ch] * rsqrtf(var2[ch] + EPS);
    s2r[nt] = s2;
    t2r[nt] = s2 * (b2[ch] - mean2[ch]) + beta2[ch];
  }
  half8 bf[4][4];
#pragma unroll
  for (int nt = 0; nt < 4; ++nt)
#pragma unroll
    for (int ks = 0; ks < 4; ++ks) {
      int colc = wave * 64 + nt * 16 + (lane & 15);
      int kb = ks * 32 + (lane >> 4) * 8;
      half8 hv;
#pragma unroll
      for (int i = 0; i < 8; ++i) hv[i] = (_Float16)W2[(size_t)(kb + i) * CO + colc];
      bf[nt][ks] = hv;
    }

  int p0 = blockIdx.x * 16;
  for (int p = 0; p < 16; ++p) {
    int pt = p0 + p;
    int m = knn[(size_t)pt * KNN + hk];
    int bb = pt >> 12;
    const float* arow = At + (size_t)pt * C + hc;
    const float* brow = Bt + ((size_t)(bb << 12) + m) * C + hc;
    float4 a0 = *(const float4*)(arow);
    float4 a1 = *(const float4*)(arow + 4);
    float4 g0 = *(const float4*)(brow);
    float4 g1 = *(const float4*)(brow + 4);
    float vv[8] = {a0.x + g0.x, a0.y + g0.y, a0.z + g0.z, a0.w + g0.w,
                   a1.x + g1.x, a1.y + g1.y, a1.z + g1.z, a1.w + g1.w};
    half8 hh;
#pragma unroll
    for (int e = 0; e < 8; ++e) hh[e] = (_Float16)fmaxf(vv[e] + beta_f[e], 0.f);
    *(half8*)&hl[hk][hc] = hh;
    __syncthreads();

    f32x4 acc[4] = {};
    half8 af[4];
#pragma unroll
    for (int ks = 0; ks < 4; ++ks)
      af[ks] = *(const half8*)&hl[lane & 15][ks * 32 + (lane >> 4) * 8];
#pragma unroll
    for (int nt = 0; nt < 4; ++nt)
#pragma unroll
      for (int ks = 0; ks < 4; ++ks)
        acc[nt] = __builtin_amdgcn_mfma_f32_16x16x32_f16(af[ks], bf[nt][ks],
                                                         acc[nt], 0, 0, 0);
#pragma unroll
    for (int nt = 0; nt < 4; ++nt) {
      float v = fmaxf(fmaxf(acc[nt][0], acc[nt][1]), fmaxf(acc[nt][2], acc[nt][3]));
      v = fmaxf(v, __shfl_xor(v, 16));
      v = fmaxf(v, __shfl_xor(v, 32));
      float o = fmaf(v, s2r[nt], t2r[nt]);
      if (lane < 16) out[(size_t)pt * CO + wave * 64 + nt * 16 + lane] = o;
    }
    __syncthreads();
  }
}

// ---------------------------------------------------------------------------
extern "C" void kernel_launch(void* const* d_in, const int* in_sizes, int n_in,
                              void* d_out, int out_size, void* d_ws, size_t ws_size,
                              hipStream_t stream) {
  const float* x = (const float*)d_in[0];
  const float* W1 = (const float*)d_in[1];
  const float* b1 = (const float*)d_in[2];
  const float* gamma1 = (const float*)d_in[3];
  const float* beta1 = (const float*)d_in[4];
  const float* mean1 = (const float*)d_in[5];
  const float* var1 = (const float*)d_in[6];
  const float* W2 = (const float*)d_in[7];
  const float* b2 = (const float*)d_in[8];
  const float* gamma2 = (const float*)d_in[9];
  const float* beta2 = (const float*)d_in[10];
  const float* mean2 = (const float*)d_in[11];
  const float* var2 = (const float*)d_in[12];
  float* out = (float*)d_out;

  char* base = (char*)d_ws;
  // region A (8 MB): pd+pi during topk, then At for the MLP
  float* At = (float*)base;                       // [M][128]
  float* pd = (float*)base;                       // [64][M] transposed
  int* pi = (int*)(base + (size_t)64 * M * 4);    // [64][M]
  // region B (8 MB): xh+xm during topk, then Bt
  float* Bt = (float*)(base + (size_t)M * C * 4);             // [M][128]
  _Float16* xh = (_Float16*)(base + (size_t)M * C * 4);       // [M][128] f16
  _Float16* xm = xh + (size_t)M * C;                          // [M][128] f16
  // tail
  float* sq = (float*)(base + (size_t)2 * M * C * 4);         // [M]
  int* knn = (int*)(sq + M);                                  // [M][16]

  k_cvt<<<dim3(M / 64), dim3(256), 0, stream>>>(x, xh, xm, sq);
  k_topk<<<dim3(B * 64 * NCHUNK), dim3(256), 0, stream>>>(xh, xm, sq, pd, pi);
  k_merge<<<dim3(M / 256), dim3(256), 0, stream>>>(pd, pi, knn);
  k_gemm1<<<dim3(M / 64, CO / 64), dim3(256), 0, stream>>>(x, W1, gamma1, var1, At, Bt);
  k_mlp<<<dim3(M / 16), dim3(256), 0, stream>>>(At, Bt, knn, W2, b1, mean1, beta1,
                                                gamma1, var1, b2, mean2, beta2,
                                                gamma2, var2, out);
}